// Round 2
// baseline (200.469 us; speedup 1.0000x reference)
//
#include <hip/hip_runtime.h>

#define NV 30000
#define NB 128
#define NS 512
#define ND 300
#define NC 300
#define CP 304     // padded C
#define KP 320     // padded K for GEMM
#define MASK_NEG -1e9f
#define SQ_EPS 1e-8f

typedef __attribute__((ext_vector_type(4))) float f32x4;
typedef __attribute__((ext_vector_type(8))) __bf16 bf16x8;

__device__ __forceinline__ unsigned short f2bf(float x){
  unsigned int u = __float_as_uint(x);
  u += 0x7FFFu + ((u >> 16) & 1u);
  return (unsigned short)(u >> 16);
}
__device__ __forceinline__ float bf2f(unsigned short h){
  return __uint_as_float(((unsigned int)h) << 16);
}

__device__ __forceinline__ float block_sum320(float v, float* red, int tid){
  red[tid] = v; __syncthreads();
  float s = 0.f;
  if (tid < 64){
    s = red[tid]+red[tid+64]+red[tid+128]+red[tid+192]+red[tid+256];
    #pragma unroll
    for (int off = 32; off > 0; off >>= 1) s += __shfl_xor(s, off);
    if (tid == 0) red[0] = s;
  }
  __syncthreads();
  s = red[0];
  __syncthreads();
  return s;
}

// ---------------- KPREP: Ws transpose->bf16, bsp, aspect capsules->t, guide->G
// blocks 0..24: Ws tiles; 25: bsp; 26..57: aspect (4 b each); 58..60: guide
__global__ __launch_bounds__(320) void kprep(
    const float* __restrict__ Ws, const float* __restrict__ Watt,
    const float* __restrict__ Gw, const float* __restrict__ bs,
    const float* __restrict__ gcap, const int* __restrict__ aspect,
    const float* __restrict__ embed, const float* __restrict__ Wa,
    const float* __restrict__ ba,
    unsigned short* __restrict__ wt, float* __restrict__ bsp,
    float* __restrict__ tbuf, float* __restrict__ gbuf)
{
  int bid = blockIdx.x, tid = threadIdx.x;
  int lane = tid & 63, wid = tid >> 6;
  __shared__ float red[320];
  if (bid < 25) {
    __shared__ float t[64][65];
    int kt = bid / 5, nt = bid - kt*5;
    #pragma unroll
    for (int i = 0; i < 13; i++){
      int idx = i*320 + tid;
      if (idx < 4096){
        int r = idx >> 6, c = idx & 63;
        int gk = kt*64 + r, gn = nt*64 + c;
        t[r][c] = (gk < ND && gn < NC) ? Ws[gk*NC + gn] : 0.f;
      }
    }
    __syncthreads();
    #pragma unroll
    for (int i = 0; i < 13; i++){
      int idx = i*320 + tid;
      if (idx < 4096){
        int n = idx >> 6, k = idx & 63;
        wt[(nt*64 + n)*KP + kt*64 + k] = f2bf(t[k][n]);
      }
    }
  } else if (bid == 25) {
    if (tid < CP) bsp[tid] = (tid < NC) ? bs[tid] : 0.f;
  } else if (bid < 58) {
    __shared__ float vec[4][CP];
    int b0 = (bid - 26) * 4;
    for (int i = tid; i < 4*CP; i += 320){
      int bi = i / CP, c = i - bi*CP;
      int a = aspect[b0 + bi];
      vec[bi][c] = (c < ND) ? embed[(size_t)a*ND + c] : 0.f;
    }
    __syncthreads();
    float z[4] = {0.f,0.f,0.f,0.f};
    if (tid < NC){
      #pragma unroll
      for (int i = 0; i < 4; i++) z[i] = ba[tid];
      for (int d = 0; d < ND; d++){
        float wv = Wa[d*NC + tid];
        #pragma unroll
        for (int i = 0; i < 4; i++) z[i] += vec[i][d]*wv;
      }
    }
    float ssv[4];
    #pragma unroll
    for (int i = 0; i < 4; i++){
      float sq = block_sum320((tid < NC) ? z[i]*z[i] : 0.f, red, tid);
      ssv[i] = (sq/(1.f+sq))/sqrtf(sq + SQ_EPS);
    }
    if (tid < CP){
      #pragma unroll
      for (int i = 0; i < 4; i++) vec[i][tid] = (tid < NC) ? z[i]*ssv[i] : 0.f;
    }
    __syncthreads();
    // hoist capsules into regs
    float capr[4][5];
    #pragma unroll
    for (int j = 0; j < 5; j++){
      int d = j*64 + lane;
      #pragma unroll
      for (int i = 0; i < 4; i++) capr[i][j] = (d < CP) ? vec[i][d] : 0.f;
    }
    // t[c] = sum_d Watt[c][d]*cap[d], coalesced row reads
    for (int c = wid; c < NC; c += 5){
      const float* wr = Watt + (size_t)c*NC;
      float a0=0.f,a1=0.f,a2=0.f,a3=0.f;
      #pragma unroll
      for (int j = 0; j < 5; j++){
        int d = j*64 + lane;
        float w = (d < ND) ? wr[d] : 0.f;
        a0 += w*capr[0][j]; a1 += w*capr[1][j];
        a2 += w*capr[2][j]; a3 += w*capr[3][j];
      }
      #pragma unroll
      for (int off = 32; off > 0; off >>= 1){
        a0 += __shfl_xor(a0, off); a1 += __shfl_xor(a1, off);
        a2 += __shfl_xor(a2, off); a3 += __shfl_xor(a3, off);
      }
      if (lane == 0){
        tbuf[(b0+0)*CP + c] = a0; tbuf[(b0+1)*CP + c] = a1;
        tbuf[(b0+2)*CP + c] = a2; tbuf[(b0+3)*CP + c] = a3;
      }
    }
    if (tid < 16){
      int bi = tid >> 2, cc = NC + (tid & 3);
      tbuf[(b0+bi)*CP + cc] = 0.f;
    }
  } else {
    __shared__ float gv[3][CP];
    int gb = bid - 58, c0 = gb*100;
    for (int i = tid; i < 3*CP; i += 320){
      int k = i / CP, c = i - k*CP;
      gv[k][c] = (c < NC) ? gcap[k*NC + c] : 0.f;
    }
    __syncthreads();
    float ssk[3];
    #pragma unroll
    for (int k = 0; k < 3; k++){
      float g = (tid < CP) ? gv[k][tid] : 0.f;
      float sq = block_sum320(g*g, red, tid);
      ssk[k] = (sq/(1.f+sq))/sqrtf(sq + SQ_EPS);
    }
    if (tid < CP){
      #pragma unroll
      for (int k = 0; k < 3; k++) gv[k][tid] *= ssk[k];
    }
    __syncthreads();
    float gr[3][5];
    #pragma unroll
    for (int j = 0; j < 5; j++){
      int d = j*64 + lane;
      #pragma unroll
      for (int k = 0; k < 3; k++) gr[k][j] = (d < CP) ? gv[k][d] : 0.f;
    }
    int cend = c0 + 100;
    for (int c = c0 + wid; c < cend; c += 5){
      const float* wr = Gw + (size_t)c*NC;
      float a0=0.f,a1=0.f,a2=0.f;
      #pragma unroll
      for (int j = 0; j < 5; j++){
        int d = j*64 + lane;
        float w = (d < ND) ? wr[d] : 0.f;
        a0 += w*gr[0][j]; a1 += w*gr[1][j]; a2 += w*gr[2][j];
      }
      #pragma unroll
      for (int off = 32; off > 0; off >>= 1){
        a0 += __shfl_xor(a0, off); a1 += __shfl_xor(a1, off); a2 += __shfl_xor(a2, off);
      }
      if (lane == 0){
        gbuf[0*CP + c] = a0; gbuf[1*CP + c] = a1; gbuf[2*CP + c] = a2;
      }
    }
    if (gb == 0 && tid < 12){
      int k = tid >> 2, cc = NC + (tid & 3);
      gbuf[k*CP + cc] = 0.f;
    }
  }
}

// ---------------- K1: E = embed @ W_s  (bf16 MFMA), BM=64, 8 waves (2x4)
#define BM 64
#define BKT 64
#define LDK 72
__global__ __launch_bounds__(512) void k1_gemm(
    const float* __restrict__ embed, const unsigned short* __restrict__ wt,
    unsigned short* __restrict__ E)
{
  __shared__ unsigned short lds_a[BM*LDK];
  __shared__ unsigned short lds_b[KP*LDK];
  int tid = threadIdx.x;
  int lane = tid & 63, wid = tid >> 6;
  int wrow = wid >> 2, wcol = wid & 3;
  int rowbase = blockIdx.x * BM;
  f32x4 acc[2][5];
  f32x4 zero = {0.f,0.f,0.f,0.f};
  #pragma unroll
  for (int m = 0; m < 2; m++)
    #pragma unroll
    for (int n = 0; n < 5; n++) acc[m][n] = zero;

  for (int k0 = 0; k0 < KP; k0 += BKT){
    #pragma unroll
    for (int r = 0; r < 2; r++){
      int id = r*512 + tid;                 // < 1024
      int row = id >> 4, k4 = (id & 15) << 2;
      int gk = k0 + k4, grow = rowbase + row;
      float4 v = {0.f,0.f,0.f,0.f};
      if (grow < NV && gk < ND) v = *(const float4*)(embed + (size_t)grow*ND + gk);
      unsigned int lo = (unsigned int)f2bf(v.x) | ((unsigned int)f2bf(v.y) << 16);
      unsigned int hi = (unsigned int)f2bf(v.z) | ((unsigned int)f2bf(v.w) << 16);
      uint2 pk; pk.x = lo; pk.y = hi;
      *(uint2*)(lds_a + row*LDK + k4) = pk;
    }
    #pragma unroll
    for (int r = 0; r < 5; r++){
      int id = r*512 + tid;                 // < 2560
      int n = id >> 3, koff = (id & 7) << 3;
      uint4 v = *(const uint4*)(wt + n*KP + k0 + koff);
      *(uint4*)(lds_b + n*LDK + koff) = v;
    }
    __syncthreads();
    #pragma unroll
    for (int kk = 0; kk < BKT; kk += 32){
      bf16x8 af[2], bfr[5];
      int kidx = kk + (lane >> 4)*8;
      int arow = wrow*32 + (lane & 15);
      int brow = wcol*80 + (lane & 15);
      #pragma unroll
      for (int m = 0; m < 2; m++) af[m] = *(const bf16x8*)(lds_a + (arow + m*16)*LDK + kidx);
      #pragma unroll
      for (int n = 0; n < 5; n++) bfr[n] = *(const bf16x8*)(lds_b + (brow + n*16)*LDK + kidx);
      #pragma unroll
      for (int m = 0; m < 2; m++)
        #pragma unroll
        for (int n = 0; n < 5; n++)
          acc[m][n] = __builtin_amdgcn_mfma_f32_16x16x32_bf16(af[m], bfr[n], acc[m][n], 0, 0, 0);
    }
    __syncthreads();
  }
  int colb = wcol*80 + (lane & 15);
  int rowb = rowbase + wrow*32 + ((lane >> 4) << 2);
  #pragma unroll
  for (int m = 0; m < 2; m++)
    #pragma unroll
    for (int n = 0; n < 5; n++)
      #pragma unroll
      for (int j = 0; j < 4; j++){
        int row = rowb + m*16 + j;
        int col = colb + n*16;
        if (row < NV && col < CP) E[(size_t)row*CP + col] = f2bf(acc[m][n][j]);
      }
}

// ---------------- K3: per-token score / u / ss (one wave per token, grid-stride)
__global__ __launch_bounds__(256) void k3_token(
    const int* __restrict__ sentence, const float* __restrict__ alphaA,
    const unsigned short* __restrict__ E, const float* __restrict__ tbuf,
    const float* __restrict__ gbuf, const float* __restrict__ bsp,
    float* __restrict__ scoreB, float* __restrict__ ssB, float* __restrict__ uuB)
{
  int tid = threadIdx.x;
  int lane = tid & 63;
  int gw0 = (blockIdx.x << 2) + (tid >> 6);
  #pragma unroll
  for (int it = 0; it < 4; it++){
    int wg = gw0 + (it << 14);
    int tok = sentence[wg];
    float al = alphaA[wg];
    int b = wg >> 9;
    const unsigned short* erow = E + (size_t)tok*CP;
    const float* trow = tbuf + b*CP;
    float sq = 0.f, sc = 0.f, u0 = 0.f, u1 = 0.f, u2 = 0.f;
    auto body = [&](int c){
      uint2 e2 = *(const uint2*)(erow + c);
      float4 tv = *(const float4*)(trow + c);
      float4 g0 = *(const float4*)(gbuf + c);
      float4 g1 = *(const float4*)(gbuf + CP + c);
      float4 g2 = *(const float4*)(gbuf + 2*CP + c);
      float4 bv = *(const float4*)(bsp + c);
      float y0 = al*bf2f((unsigned short)(e2.x & 0xffffu)) + bv.x;
      float y1 = al*bf2f((unsigned short)(e2.x >> 16)) + bv.y;
      float y2 = al*bf2f((unsigned short)(e2.y & 0xffffu)) + bv.z;
      float y3 = al*bf2f((unsigned short)(e2.y >> 16)) + bv.w;
      sq += y0*y0 + y1*y1 + y2*y2 + y3*y3;
      sc += y0*tv.x + y1*tv.y + y2*tv.z + y3*tv.w;
      u0 += y0*g0.x + y1*g0.y + y2*g0.z + y3*g0.w;
      u1 += y0*g1.x + y1*g1.y + y2*g1.z + y3*g1.w;
      u2 += y0*g2.x + y1*g2.y + y2*g2.z + y3*g2.w;
    };
    body(lane << 2);
    if (lane < 12) body(256 + (lane << 2));
    #pragma unroll
    for (int off = 32; off > 0; off >>= 1){
      sq += __shfl_xor(sq, off);
      sc += __shfl_xor(sc, off);
      u0 += __shfl_xor(u0, off);
      u1 += __shfl_xor(u1, off);
      u2 += __shfl_xor(u2, off);
    }
    if (lane == 0){
      float ssv = (sq/(1.f+sq))/sqrtf(sq + SQ_EPS);
      scoreB[wg] = (tok != 0) ? ssv*sc : MASK_NEG;
      ssB[wg] = ssv;
      uuB[wg*3+0] = ssv*u0;
      uuB[wg*3+1] = ssv*u1;
      uuB[wg*3+2] = ssv*u2;
    }
  }
}

// ---------------- K4: per-b softmax over S, k-softmax, final weights (+CNT reset)
__global__ __launch_bounds__(512) void k4_softmax(
    const float* __restrict__ scoreB, const float* __restrict__ uuB,
    const float* __restrict__ ssB, const float* __restrict__ alphaA,
    const float* __restrict__ scale_p,
    float* __restrict__ coef, float* __restrict__ sb, int* __restrict__ CNT)
{
  int b = blockIdx.x, tid = threadIdx.x;
  int idx = (b << 9) + tid;
  __shared__ float red[512];
  if (tid == 0) CNT[b] = 0;
  float scv = scoreB[idx];
  red[tid] = scv; __syncthreads();
  if (tid < 64){
    float s = red[tid];
    #pragma unroll
    for (int o = 64; o < 512; o += 64) s = fmaxf(s, red[tid+o]);
    #pragma unroll
    for (int off = 32; off > 0; off >>= 1) s = fmaxf(s, __shfl_xor(s, off));
    if (tid == 0) red[0] = s;
  }
  __syncthreads();
  float m = red[0];
  __syncthreads();
  float e = expf(scv - m);
  red[tid] = e; __syncthreads();
  if (tid < 64){
    float s = 0.f;
    #pragma unroll
    for (int o = 0; o < 512; o += 64) s += red[tid+o];
    #pragma unroll
    for (int off = 32; off > 0; off >>= 1) s += __shfl_xor(s, off);
    if (tid == 0) red[0] = s;
  }
  __syncthreads();
  float Z = red[0];
  __syncthreads();
  float nw = e / Z;
  float v0 = uuB[idx*3+0], v1 = uuB[idx*3+1], v2 = uuB[idx*3+2];
  float mk = fmaxf(v0, fmaxf(v1, v2));
  float e0 = expf(v0-mk), e1 = expf(v1-mk), e2 = expf(v2-mk);
  float wf = nw * scale_p[0] / (e0+e1+e2);
  float w0 = e0*wf, w1 = e1*wf, w2 = e2*wf;
  float ssv = ssB[idx];
  float ca = ssv * alphaA[idx];
  coef[idx*3+0] = w0*ca; coef[idx*3+1] = w1*ca; coef[idx*3+2] = w2*ca;
  float s0 = w0*ssv, s1 = w1*ssv, s2 = w2*ssv;
  red[tid] = s0; __syncthreads();
  if (tid < 64){
    float s = 0.f;
    #pragma unroll
    for (int o = 0; o < 512; o += 64) s += red[tid+o];
    #pragma unroll
    for (int off = 32; off > 0; off >>= 1) s += __shfl_xor(s, off);
    if (tid == 0) sb[b*3+0] = s;
  }
  __syncthreads();
  red[tid] = s1; __syncthreads();
  if (tid < 64){
    float s = 0.f;
    #pragma unroll
    for (int o = 0; o < 512; o += 64) s += red[tid+o];
    #pragma unroll
    for (int off = 32; off > 0; off >>= 1) s += __shfl_xor(s, off);
    if (tid == 0) sb[b*3+1] = s;
  }
  __syncthreads();
  red[tid] = s2; __syncthreads();
  if (tid < 64){
    float s = 0.f;
    #pragma unroll
    for (int o = 0; o < 512; o += 64) s += red[tid+o];
    #pragma unroll
    for (int off = 32; off > 0; off >>= 1) s += __shfl_xor(s, off);
    if (tid == 0) sb[b*3+2] = s;
  }
}

// ---------------- K5: weighted gather-sum -> partials; last block per b finalizes
__global__ __launch_bounds__(320) void k5_accum(
    const int* __restrict__ sentence, const unsigned short* __restrict__ E,
    const float* __restrict__ coef, float* __restrict__ part,
    int* __restrict__ CNT, const float* __restrict__ sb,
    const float* __restrict__ bsp, float* __restrict__ out)
{
  int bid = blockIdx.x;       // b*4 + ch
  int tid = threadIdx.x;
  int b = bid >> 2;
  int tbase = bid << 7;
  __shared__ int toks[128];
  __shared__ float cfs[384];
  __shared__ float red[320];
  __shared__ int sflag;
  if (tid < 128) toks[tid] = sentence[tbase + tid];
  cfs[tid] = coef[tbase*3 + tid];
  if (tid < 64) cfs[320+tid] = coef[tbase*3 + 320 + tid];
  __syncthreads();
  if (tid < CP){
    float a0 = 0.f, a1 = 0.f, a2 = 0.f;
    for (int i = 0; i < 128; i++){
      float ev = bf2f(E[(size_t)toks[i]*CP + tid]);
      a0 += cfs[i*3+0]*ev;
      a1 += cfs[i*3+1]*ev;
      a2 += cfs[i*3+2]*ev;
    }
    float* p = part + (size_t)bid*3*CP;
    p[tid] = a0; p[CP+tid] = a1; p[2*CP+tid] = a2;
  }
  __threadfence();
  __syncthreads();
  if (tid == 0) sflag = atomicAdd(&CNT[b], 1);
  __syncthreads();
  if (sflag == 3){
    __threadfence();
    #pragma unroll
    for (int k = 0; k < 3; k++){
      float v = 0.f;
      if (tid < CP){
        v = sb[b*3+k]*bsp[tid];
        #pragma unroll
        for (int ch = 0; ch < 4; ch++)
          v += part[((size_t)(b*4+ch)*3 + k)*CP + tid];
      }
      red[tid] = v*v; __syncthreads();
      if (tid < 64){
        float s = red[tid]+red[tid+64]+red[tid+128]+red[tid+192]+red[tid+256];
        #pragma unroll
        for (int off = 32; off > 0; off >>= 1) s += __shfl_xor(s, off);
        if (tid == 0){
          float sq = s;
          out[b*3+k] = (sq/(1.f+sq))*sqrtf(sq)/sqrtf(sq + SQ_EPS);
        }
      }
      __syncthreads();
    }
  }
}

extern "C" void kernel_launch(void* const* d_in, const int* in_sizes, int n_in,
                              void* d_out, int out_size, void* d_ws, size_t ws_size,
                              hipStream_t stream)
{
  (void)in_sizes; (void)n_in; (void)out_size; (void)ws_size;
  const int*   sentence = (const int*)d_in[0];
  const int*   aspect   = (const int*)d_in[1];
  const float* alpha    = (const float*)d_in[2];
  const float* embed    = (const float*)d_in[3];
  const float* Ws       = (const float*)d_in[4];
  const float* bs       = (const float*)d_in[5];
  const float* Wa       = (const float*)d_in[6];
  const float* ba       = (const float*)d_in[7];
  const float* Watt     = (const float*)d_in[8];
  const float* gcap     = (const float*)d_in[9];
  const float* gw       = (const float*)d_in[10];
  const float* scale    = (const float*)d_in[11];
  float* out = (float*)d_out;

  char* w = (char*)d_ws;
  auto alloc = [&](size_t bytes)->char*{
    char* p = w; w += (bytes + 255) & ~(size_t)255; return p;
  };
  unsigned short* WT  = (unsigned short*)alloc((size_t)KP*KP*2);
  unsigned short* E   = (unsigned short*)alloc((size_t)NV*CP*2);
  float* BSP = (float*)alloc(CP*4);
  float* TBF = (float*)alloc((size_t)NB*CP*4);
  float* GBF = (float*)alloc(3*CP*4);
  float* SCO = (float*)alloc((size_t)NB*NS*4);
  float* SSB = (float*)alloc((size_t)NB*NS*4);
  float* UUB = (float*)alloc((size_t)NB*NS*3*4);
  float* COF = (float*)alloc((size_t)NB*NS*3*4);
  float* SBB = (float*)alloc(NB*3*4);
  float* PRT = (float*)alloc((size_t)NB*4*3*CP*4);
  int*   CNT = (int*)alloc(NB*4);

  kprep<<<61, 320, 0, stream>>>(Ws, Watt, gw, bs, gcap, aspect, embed, Wa, ba,
                                WT, BSP, TBF, GBF);
  k1_gemm<<<(NV + BM - 1)/BM, 512, 0, stream>>>(embed, WT, E);
  k3_token<<<4096, 256, 0, stream>>>(sentence, alpha, E, TBF, GBF, BSP, SCO, SSB, UUB);
  k4_softmax<<<NB, 512, 0, stream>>>(SCO, UUB, SSB, alpha, scale, COF, SBB, CNT);
  k5_accum<<<NB*4, 320, 0, stream>>>(sentence, E, COF, PRT, CNT, SBB, BSP, out);
}

// Round 3
// 132.862 us; speedup vs baseline: 1.5088x; 1.5088x over previous
//
#include <hip/hip_runtime.h>

#define NV 30000
#define NB 128
#define NS 512
#define ND 300
#define NC 300
#define CP 304     // padded C (f32 buffers)
#define KP 320     // padded K for k1 GEMM
#define EP 320     // E row stride (bf16, padded C)
#define ETW 136    // EtT width: 0..127 = e.t_b, 128..130 = e.g_k, 131 = e.bs, 132 = e.e
#define MASK_NEG -1e9f
#define SQ_EPS 1e-8f

typedef __attribute__((ext_vector_type(4))) float f32x4;
typedef __attribute__((ext_vector_type(8))) __bf16 bf16x8;

__device__ __forceinline__ unsigned short f2bf(float x){
  unsigned int u = __float_as_uint(x);
  u += 0x7FFFu + ((u >> 16) & 1u);
  return (unsigned short)(u >> 16);
}
__device__ __forceinline__ float bf2f(unsigned short h){
  return __uint_as_float(((unsigned int)h) << 16);
}

__device__ __forceinline__ float block_sum320(float v, float* red, int tid){
  red[tid] = v; __syncthreads();
  float s = 0.f;
  if (tid < 64){
    s = red[tid]+red[tid+64]+red[tid+128]+red[tid+192]+red[tid+256];
    #pragma unroll
    for (int off = 32; off > 0; off >>= 1) s += __shfl_xor(s, off);
    if (tid == 0) red[0] = s;
  }
  __syncthreads();
  s = red[0];
  __syncthreads();
  return s;
}

__device__ __forceinline__ float bsum512(float v, float* red, int tid){
  red[tid] = v; __syncthreads();
  float s = 0.f;
  if (tid < 64){
    s = red[tid]+red[tid+64]+red[tid+128]+red[tid+192]
      + red[tid+256]+red[tid+320]+red[tid+384]+red[tid+448];
    #pragma unroll
    for (int off = 32; off > 0; off >>= 1) s += __shfl_xor(s, off);
    if (tid == 0) red[0] = s;
  }
  __syncthreads();
  s = red[0];
  __syncthreads();
  return s;
}

__device__ __forceinline__ float bmax512(float v, float* red, int tid){
  red[tid] = v; __syncthreads();
  float s = MASK_NEG;
  if (tid < 64){
    s = red[tid];
    #pragma unroll
    for (int o = 64; o < 512; o += 64) s = fmaxf(s, red[tid+o]);
    #pragma unroll
    for (int off = 32; off > 0; off >>= 1) s = fmaxf(s, __shfl_xor(s, off));
    if (tid == 0) red[0] = s;
  }
  __syncthreads();
  s = red[0];
  __syncthreads();
  return s;
}

// ---------------- KPREP: Ws transpose->bf16, bsp(320), aspect capsules->t, guide->G
__global__ __launch_bounds__(320) void kprep(
    const float* __restrict__ Ws, const float* __restrict__ Watt,
    const float* __restrict__ Gw, const float* __restrict__ bs,
    const float* __restrict__ gcap, const int* __restrict__ aspect,
    const float* __restrict__ embed, const float* __restrict__ Wa,
    const float* __restrict__ ba,
    unsigned short* __restrict__ wt, float* __restrict__ bsp,
    float* __restrict__ tbuf, float* __restrict__ gbuf)
{
  int bid = blockIdx.x, tid = threadIdx.x;
  int lane = tid & 63, wid = tid >> 6;
  __shared__ float red[320];
  if (bid < 25) {
    __shared__ float t[64][65];
    int kt = bid / 5, nt = bid - kt*5;
    #pragma unroll
    for (int i = 0; i < 13; i++){
      int idx = i*320 + tid;
      if (idx < 4096){
        int r = idx >> 6, c = idx & 63;
        int gk = kt*64 + r, gn = nt*64 + c;
        t[r][c] = (gk < ND && gn < NC) ? Ws[gk*NC + gn] : 0.f;
      }
    }
    __syncthreads();
    #pragma unroll
    for (int i = 0; i < 13; i++){
      int idx = i*320 + tid;
      if (idx < 4096){
        int n = idx >> 6, k = idx & 63;
        wt[(nt*64 + n)*KP + kt*64 + k] = f2bf(t[k][n]);
      }
    }
  } else if (bid == 25) {
    bsp[tid] = (tid < NC) ? bs[tid] : 0.f;   // 320 wide
  } else if (bid < 58) {
    __shared__ float vec[4][CP];
    int b0 = (bid - 26) * 4;
    for (int i = tid; i < 4*CP; i += 320){
      int bi = i / CP, c = i - bi*CP;
      int a = aspect[b0 + bi];
      vec[bi][c] = (c < ND) ? embed[(size_t)a*ND + c] : 0.f;
    }
    __syncthreads();
    float z[4] = {0.f,0.f,0.f,0.f};
    if (tid < NC){
      #pragma unroll
      for (int i = 0; i < 4; i++) z[i] = ba[tid];
      for (int d = 0; d < ND; d++){
        float wv = Wa[d*NC + tid];
        #pragma unroll
        for (int i = 0; i < 4; i++) z[i] += vec[i][d]*wv;
      }
    }
    float ssv[4];
    #pragma unroll
    for (int i = 0; i < 4; i++){
      float sq = block_sum320((tid < NC) ? z[i]*z[i] : 0.f, red, tid);
      ssv[i] = (sq/(1.f+sq))/sqrtf(sq + SQ_EPS);
    }
    if (tid < CP){
      #pragma unroll
      for (int i = 0; i < 4; i++) vec[i][tid] = (tid < NC) ? z[i]*ssv[i] : 0.f;
    }
    __syncthreads();
    float capr[4][5];
    #pragma unroll
    for (int j = 0; j < 5; j++){
      int d = j*64 + lane;
      #pragma unroll
      for (int i = 0; i < 4; i++) capr[i][j] = (d < CP) ? vec[i][d] : 0.f;
    }
    for (int c = wid; c < NC; c += 5){
      const float* wr = Watt + (size_t)c*NC;
      float a0=0.f,a1=0.f,a2=0.f,a3=0.f;
      #pragma unroll
      for (int j = 0; j < 5; j++){
        int d = j*64 + lane;
        float w = (d < ND) ? wr[d] : 0.f;
        a0 += w*capr[0][j]; a1 += w*capr[1][j];
        a2 += w*capr[2][j]; a3 += w*capr[3][j];
      }
      #pragma unroll
      for (int off = 32; off > 0; off >>= 1){
        a0 += __shfl_xor(a0, off); a1 += __shfl_xor(a1, off);
        a2 += __shfl_xor(a2, off); a3 += __shfl_xor(a3, off);
      }
      if (lane == 0){
        tbuf[(b0+0)*CP + c] = a0; tbuf[(b0+1)*CP + c] = a1;
        tbuf[(b0+2)*CP + c] = a2; tbuf[(b0+3)*CP + c] = a3;
      }
    }
    if (tid < 16){
      int bi = tid >> 2, cc = NC + (tid & 3);
      tbuf[(b0+bi)*CP + cc] = 0.f;
    }
  } else {
    __shared__ float gv[3][CP];
    int gb = bid - 58, c0 = gb*100;
    for (int i = tid; i < 3*CP; i += 320){
      int k = i / CP, c = i - k*CP;
      gv[k][c] = (c < NC) ? gcap[k*NC + c] : 0.f;
    }
    __syncthreads();
    float ssk[3];
    #pragma unroll
    for (int k = 0; k < 3; k++){
      float g = (tid < CP) ? gv[k][tid] : 0.f;
      float sq = block_sum320(g*g, red, tid);
      ssk[k] = (sq/(1.f+sq))/sqrtf(sq + SQ_EPS);
    }
    if (tid < CP){
      #pragma unroll
      for (int k = 0; k < 3; k++) gv[k][tid] *= ssk[k];
    }
    __syncthreads();
    float gr[3][5];
    #pragma unroll
    for (int j = 0; j < 5; j++){
      int d = j*64 + lane;
      #pragma unroll
      for (int k = 0; k < 3; k++) gr[k][j] = (d < CP) ? gv[k][d] : 0.f;
    }
    int cend = c0 + 100;
    for (int c = c0 + wid; c < cend; c += 5){
      const float* wr = Gw + (size_t)c*NC;
      float a0=0.f,a1=0.f,a2=0.f;
      #pragma unroll
      for (int j = 0; j < 5; j++){
        int d = j*64 + lane;
        float w = (d < ND) ? wr[d] : 0.f;
        a0 += w*gr[0][j]; a1 += w*gr[1][j]; a2 += w*gr[2][j];
      }
      #pragma unroll
      for (int off = 32; off > 0; off >>= 1){
        a0 += __shfl_xor(a0, off); a1 += __shfl_xor(a1, off); a2 += __shfl_xor(a2, off);
      }
      if (lane == 0){
        gbuf[0*CP + c] = a0; gbuf[1*CP + c] = a1; gbuf[2*CP + c] = a2;
      }
    }
    if (gb == 0 && tid < 12){
      int k = tid >> 2, cc = NC + (tid & 3);
      gbuf[k*CP + cc] = 0.f;
    }
  }
}

// ---------------- K1: E = embed @ W_s (bf16 MFMA) + per-row e.e into EtT col 132
#define BM 64
#define BKT 64
#define LDK 72
__global__ __launch_bounds__(512) void k1_gemm(
    const float* __restrict__ embed, const unsigned short* __restrict__ wt,
    unsigned short* __restrict__ E, float* __restrict__ EtT)
{
  __shared__ unsigned short lds_a[BM*LDK];
  __shared__ unsigned short lds_b[KP*LDK];
  __shared__ float e2part[4][BM];
  int tid = threadIdx.x;
  int lane = tid & 63, wid = tid >> 6;
  int wrow = wid >> 2, wcol = wid & 3;
  int rowbase = blockIdx.x * BM;
  f32x4 acc[2][5];
  f32x4 zero = {0.f,0.f,0.f,0.f};
  #pragma unroll
  for (int m = 0; m < 2; m++)
    #pragma unroll
    for (int n = 0; n < 5; n++) acc[m][n] = zero;

  for (int k0 = 0; k0 < KP; k0 += BKT){
    #pragma unroll
    for (int r = 0; r < 2; r++){
      int id = r*512 + tid;                 // < 1024
      int row = id >> 4, k4 = (id & 15) << 2;
      int gk = k0 + k4, grow = rowbase + row;
      float4 v = {0.f,0.f,0.f,0.f};
      if (grow < NV && gk < ND) v = *(const float4*)(embed + (size_t)grow*ND + gk);
      unsigned int lo = (unsigned int)f2bf(v.x) | ((unsigned int)f2bf(v.y) << 16);
      unsigned int hi = (unsigned int)f2bf(v.z) | ((unsigned int)f2bf(v.w) << 16);
      uint2 pk; pk.x = lo; pk.y = hi;
      *(uint2*)(lds_a + row*LDK + k4) = pk;
    }
    #pragma unroll
    for (int r = 0; r < 5; r++){
      int id = r*512 + tid;                 // < 2560
      int n = id >> 3, koff = (id & 7) << 3;
      uint4 v = *(const uint4*)(wt + n*KP + k0 + koff);
      *(uint4*)(lds_b + n*LDK + koff) = v;
    }
    __syncthreads();
    #pragma unroll
    for (int kk = 0; kk < BKT; kk += 32){
      bf16x8 af[2], bfr[5];
      int kidx = kk + (lane >> 4)*8;
      int arow = wrow*32 + (lane & 15);
      int brow = wcol*80 + (lane & 15);
      #pragma unroll
      for (int m = 0; m < 2; m++) af[m] = *(const bf16x8*)(lds_a + (arow + m*16)*LDK + kidx);
      #pragma unroll
      for (int n = 0; n < 5; n++) bfr[n] = *(const bf16x8*)(lds_b + (brow + n*16)*LDK + kidx);
      #pragma unroll
      for (int m = 0; m < 2; m++)
        #pragma unroll
        for (int n = 0; n < 5; n++)
          acc[m][n] = __builtin_amdgcn_mfma_f32_16x16x32_bf16(af[m], bfr[n], acc[m][n], 0, 0, 0);
    }
    __syncthreads();
  }
  int colb = wcol*80 + (lane & 15);
  int rowb = rowbase + wrow*32 + ((lane >> 4) << 2);
  #pragma unroll
  for (int m = 0; m < 2; m++)
    #pragma unroll
    for (int n = 0; n < 5; n++)
      #pragma unroll
      for (int j = 0; j < 4; j++){
        int row = rowb + m*16 + j;
        int col = colb + n*16;
        if (row < NV) E[(size_t)row*EP + col] = f2bf(acc[m][n][j]);
      }
  // e.e per row: sum acc^2 over this wave's 80 cols, reduce across 16-lane group,
  // then deterministic combine over the 4 wcol waves.
  #pragma unroll
  for (int m = 0; m < 2; m++)
    #pragma unroll
    for (int j = 0; j < 4; j++){
      float p = 0.f;
      #pragma unroll
      for (int n = 0; n < 5; n++){ float t = acc[m][n][j]; p += t*t; }
      #pragma unroll
      for (int off = 1; off < 16; off <<= 1) p += __shfl_xor(p, off);
      if ((lane & 15) == 0)
        e2part[wcol][wrow*32 + m*16 + ((lane >> 4) << 2) + j] = p;
    }
  __syncthreads();
  if (tid < BM){
    int grow = rowbase + tid;
    if (grow < NV){
      float s = e2part[0][tid] + e2part[1][tid] + e2part[2][tid] + e2part[3][tid];
      EtT[(size_t)grow*ETW + 132] = s;
    }
  }
}

// ---------------- K1B: EtT[:,0:132] = [E ; bs] @ [T | g0 g1 g2 | bs]^T
#define BM2 128
#define BN2 160
#define LDK2 72
__global__ __launch_bounds__(512) void k1b_gemm(
    const unsigned short* __restrict__ E, const float* __restrict__ tbuf,
    const float* __restrict__ gbuf, const float* __restrict__ bsp,
    float* __restrict__ EtT)
{
  __shared__ unsigned short la[BM2*LDK2];
  __shared__ unsigned short lb[BN2*LDK2];
  int tid = threadIdx.x;
  int lane = tid & 63, wid = tid >> 6;
  int wrow = wid >> 1, wcol = wid & 1;    // 4 x 2
  int rowbase = blockIdx.x * BM2;
  f32x4 acc[2][5];
  f32x4 zero = {0.f,0.f,0.f,0.f};
  #pragma unroll
  for (int m = 0; m < 2; m++)
    #pragma unroll
    for (int n = 0; n < 5; n++) acc[m][n] = zero;

  for (int k0 = 0; k0 < EP; k0 += 64){
    // A: 128 rows x 64 k (bf16 from E, or bs row, or zeros)
    #pragma unroll
    for (int r = 0; r < 2; r++){
      int id = r*512 + tid;                 // < 1024
      int row = id >> 3, koff = (id & 7) << 3;
      int grow = rowbase + row, gk = k0 + koff;
      uint4 v = {0u,0u,0u,0u};
      if (grow < NV){
        v = *(const uint4*)(E + (size_t)grow*EP + gk);
      } else if (grow == NV){
        float4 f0 = *(const float4*)(bsp + gk);
        float4 f1 = *(const float4*)(bsp + gk + 4);
        v.x = (unsigned int)f2bf(f0.x) | ((unsigned int)f2bf(f0.y) << 16);
        v.y = (unsigned int)f2bf(f0.z) | ((unsigned int)f2bf(f0.w) << 16);
        v.z = (unsigned int)f2bf(f1.x) | ((unsigned int)f2bf(f1.y) << 16);
        v.w = (unsigned int)f2bf(f1.z) | ((unsigned int)f2bf(f1.w) << 16);
      }
      *(uint4*)(la + row*LDK2 + koff) = v;
    }
    // B: 160 n x 64 k from f32 sources
    #pragma unroll
    for (int r = 0; r < 5; r++){
      int id = r*512 + tid;                 // < 2560
      int n = id >> 4, k4 = (id & 15) << 2;
      int gk = k0 + k4;
      float4 f = {0.f,0.f,0.f,0.f};
      if (gk < CP){
        if (n < 128)       f = *(const float4*)(tbuf + (size_t)n*CP + gk);
        else if (n < 131)  f = *(const float4*)(gbuf + (size_t)(n-128)*CP + gk);
        else if (n == 131) f = *(const float4*)(bsp + gk);
      }
      uint2 pk;
      pk.x = (unsigned int)f2bf(f.x) | ((unsigned int)f2bf(f.y) << 16);
      pk.y = (unsigned int)f2bf(f.z) | ((unsigned int)f2bf(f.w) << 16);
      *(uint2*)(lb + n*LDK2 + k4) = pk;
    }
    __syncthreads();
    #pragma unroll
    for (int kk = 0; kk < 64; kk += 32){
      bf16x8 af[2], bfr[5];
      int kidx = kk + (lane >> 4)*8;
      int arow = wrow*32 + (lane & 15);
      int brow = wcol*80 + (lane & 15);
      #pragma unroll
      for (int m = 0; m < 2; m++) af[m] = *(const bf16x8*)(la + (arow + m*16)*LDK2 + kidx);
      #pragma unroll
      for (int n = 0; n < 5; n++) bfr[n] = *(const bf16x8*)(lb + (brow + n*16)*LDK2 + kidx);
      #pragma unroll
      for (int m = 0; m < 2; m++)
        #pragma unroll
        for (int n = 0; n < 5; n++)
          acc[m][n] = __builtin_amdgcn_mfma_f32_16x16x32_bf16(af[m], bfr[n], acc[m][n], 0, 0, 0);
    }
    __syncthreads();
  }
  int colb = wcol*80 + (lane & 15);
  int rowb = rowbase + wrow*32 + ((lane >> 4) << 2);
  #pragma unroll
  for (int m = 0; m < 2; m++)
    #pragma unroll
    for (int n = 0; n < 5; n++)
      #pragma unroll
      for (int j = 0; j < 4; j++){
        int row = rowb + m*16 + j;
        int col = colb + n*16;
        if (row <= NV && col < 132) EtT[(size_t)row*ETW + col] = acc[m][n][j];
      }
}

// ---------------- K45: per-b stats -> softmax -> weighted E-row gather -> out
__global__ __launch_bounds__(512) void k45(
    const int* __restrict__ sentence, const float* __restrict__ alpha,
    const float* __restrict__ scale_p, const unsigned short* __restrict__ E,
    const float* __restrict__ EtT, const float* __restrict__ bsp,
    float* __restrict__ out)
{
  int b = blockIdx.x, tid = threadIdx.x;
  int lane = tid & 63, w = tid >> 6;
  __shared__ float red[512];
  __shared__ float cfs[NS*3];
  __shared__ int toksh[NS];
  __shared__ float cap8[8][3][CP];
  __shared__ float vall[3*CP];

  int idx = (b << 9) + tid;
  int tok = sentence[idx];
  float al = alpha[idx];
  toksh[tid] = tok;
  const float* er = EtT + (size_t)tok*ETW;
  float e2v = er[132];
  float et  = er[b];
  float g0  = er[128], g1 = er[129], g2 = er[130];
  float ebs = er[131];
  const float* br = EtT + (size_t)NV*ETW;
  float bst = br[b];
  float bsg0 = br[128], bsg1 = br[129], bsg2 = br[130], bs2 = br[131];

  float sq  = al*al*e2v + 2.f*al*ebs + bs2;
  float ssv = (sq/(1.f+sq))/sqrtf(sq + SQ_EPS);
  float scv = (tok != 0) ? ssv*(al*et + bst) : MASK_NEG;
  float u0 = ssv*(al*g0 + bsg0);
  float u1 = ssv*(al*g1 + bsg1);
  float u2 = ssv*(al*g2 + bsg2);

  float m = bmax512(scv, red, tid);
  float e = expf(scv - m);
  float Z = bsum512(e, red, tid);
  float nw = e / Z;
  float mk = fmaxf(u0, fmaxf(u1, u2));
  float e0 = expf(u0-mk), e1 = expf(u1-mk), e2 = expf(u2-mk);
  float wf = nw * scale_p[0] / (e0+e1+e2);
  float w0 = e0*wf, w1 = e1*wf, w2 = e2*wf;
  float ca = ssv * al;
  cfs[tid*3+0] = w0*ca; cfs[tid*3+1] = w1*ca; cfs[tid*3+2] = w2*ca;
  float sb0 = bsum512(w0*ssv, red, tid);
  float sb1 = bsum512(w1*ssv, red, tid);
  float sb2 = bsum512(w2*ssv, red, tid);
  __syncthreads();

  // gather phase: wave w handles tokens [w*64, w*64+64)
  f32x4 A0 = {0.f,0.f,0.f,0.f}, A1 = A0, A2 = A0, R0 = A0, R1 = A0, R2 = A0;
  int c0 = lane << 2;
  int c1 = 256 + (lane << 2);
  bool rem = lane < 12;
  int base = w << 6;
  #pragma unroll 4
  for (int i = 0; i < 64; i++){
    int s = base + i;
    int t = toksh[s];
    const unsigned short* erow = E + (size_t)t*EP;
    uint2 ev = *(const uint2*)(erow + c0);
    float cf0 = cfs[s*3+0], cf1 = cfs[s*3+1], cf2 = cfs[s*3+2];
    f32x4 y;
    y[0] = bf2f((unsigned short)(ev.x & 0xffffu));
    y[1] = bf2f((unsigned short)(ev.x >> 16));
    y[2] = bf2f((unsigned short)(ev.y & 0xffffu));
    y[3] = bf2f((unsigned short)(ev.y >> 16));
    A0 += cf0*y; A1 += cf1*y; A2 += cf2*y;
    if (rem){
      uint2 ev2 = *(const uint2*)(erow + c1);
      f32x4 yr;
      yr[0] = bf2f((unsigned short)(ev2.x & 0xffffu));
      yr[1] = bf2f((unsigned short)(ev2.x >> 16));
      yr[2] = bf2f((unsigned short)(ev2.y & 0xffffu));
      yr[3] = bf2f((unsigned short)(ev2.y >> 16));
      R0 += cf0*yr; R1 += cf1*yr; R2 += cf2*yr;
    }
  }
  *(f32x4*)&cap8[w][0][c0] = A0;
  *(f32x4*)&cap8[w][1][c0] = A1;
  *(f32x4*)&cap8[w][2][c0] = A2;
  if (rem){
    *(f32x4*)&cap8[w][0][c1] = R0;
    *(f32x4*)&cap8[w][1][c1] = R1;
    *(f32x4*)&cap8[w][2][c1] = R2;
  }
  __syncthreads();
  float sbk[3] = {sb0, sb1, sb2};
  for (int p = tid; p < 3*CP; p += 512){
    int k = p / CP, c = p - k*CP;
    float v = sbk[k]*bsp[c];
    #pragma unroll
    for (int w8 = 0; w8 < 8; w8++) v += cap8[w8][k][c];
    vall[p] = v;
  }
  __syncthreads();
  #pragma unroll
  for (int k = 0; k < 3; k++){
    float x = 0.f;
    if (tid < CP){ float t = vall[k*CP + tid]; x = t*t; }
    float s = bsum512(x, red, tid);
    if (tid == 0){
      out[b*3 + k] = (s/(1.f+s))*sqrtf(s)/sqrtf(s + SQ_EPS);
    }
  }
}

extern "C" void kernel_launch(void* const* d_in, const int* in_sizes, int n_in,
                              void* d_out, int out_size, void* d_ws, size_t ws_size,
                              hipStream_t stream)
{
  (void)in_sizes; (void)n_in; (void)out_size; (void)ws_size;
  const int*   sentence = (const int*)d_in[0];
  const int*   aspect   = (const int*)d_in[1];
  const float* alpha    = (const float*)d_in[2];
  const float* embed    = (const float*)d_in[3];
  const float* Ws       = (const float*)d_in[4];
  const float* bs       = (const float*)d_in[5];
  const float* Wa       = (const float*)d_in[6];
  const float* ba       = (const float*)d_in[7];
  const float* Watt     = (const float*)d_in[8];
  const float* gcap     = (const float*)d_in[9];
  const float* gw       = (const float*)d_in[10];
  const float* scale    = (const float*)d_in[11];
  float* out = (float*)d_out;

  char* w = (char*)d_ws;
  auto alloc = [&](size_t bytes)->char*{
    char* p = w; w += (bytes + 255) & ~(size_t)255; return p;
  };
  unsigned short* WT  = (unsigned short*)alloc((size_t)KP*KP*2);
  unsigned short* E   = (unsigned short*)alloc((size_t)NV*EP*2);
  float* ETT = (float*)alloc((size_t)(NV+1)*ETW*4);
  float* BSP = (float*)alloc(320*4);
  float* TBF = (float*)alloc((size_t)NB*CP*4);
  float* GBF = (float*)alloc(3*CP*4);

  kprep<<<61, 320, 0, stream>>>(Ws, Watt, gw, bs, gcap, aspect, embed, Wa, ba,
                                WT, BSP, TBF, GBF);
  k1_gemm<<<(NV + BM - 1)/BM, 512, 0, stream>>>(embed, WT, E, ETT);
  k1b_gemm<<<(NV + 1 + BM2 - 1)/BM2, 512, 0, stream>>>(E, TBF, GBF, BSP, ETT);
  k45<<<NB, 512, 0, stream>>>(sentence, alpha, scale, E, ETT, BSP, out);
}

// Round 4
// 106.485 us; speedup vs baseline: 1.8826x; 1.2477x over previous
//
#include <hip/hip_runtime.h>

#define NV 30000
#define NB 128
#define NS 512
#define ND 300
#define NC 300
#define CP 304     // padded C (f32 buffers)
#define KP 320     // padded K for k1 GEMM
#define EP 320     // E row stride (bf16, padded C)
#define ETW 136    // EtT width: 0..127 = e.t_b, 128..130 = e.g_k, 131 = e.bs, 132 = e.e
#define MASK_NEG -1e9f
#define SQ_EPS 1e-8f

typedef __attribute__((ext_vector_type(4))) float f32x4;
typedef __attribute__((ext_vector_type(8))) __bf16 bf16x8;

__device__ __forceinline__ unsigned short f2bf(float x){
  unsigned int u = __float_as_uint(x);
  u += 0x7FFFu + ((u >> 16) & 1u);
  return (unsigned short)(u >> 16);
}
__device__ __forceinline__ float bf2f(unsigned short h){
  return __uint_as_float(((unsigned int)h) << 16);
}

__device__ __forceinline__ float bsum512(float v, float* red, int tid){
  red[tid] = v; __syncthreads();
  float s = 0.f;
  if (tid < 64){
    s = red[tid]+red[tid+64]+red[tid+128]+red[tid+192]
      + red[tid+256]+red[tid+320]+red[tid+384]+red[tid+448];
    #pragma unroll
    for (int off = 32; off > 0; off >>= 1) s += __shfl_xor(s, off);
    if (tid == 0) red[0] = s;
  }
  __syncthreads();
  s = red[0];
  __syncthreads();
  return s;
}

__device__ __forceinline__ float bmax512(float v, float* red, int tid){
  red[tid] = v; __syncthreads();
  float s = MASK_NEG;
  if (tid < 64){
    s = red[tid];
    #pragma unroll
    for (int o = 64; o < 512; o += 64) s = fmaxf(s, red[tid+o]);
    #pragma unroll
    for (int off = 32; off > 0; off >>= 1) s = fmaxf(s, __shfl_xor(s, off));
    if (tid == 0) red[0] = s;
  }
  __syncthreads();
  s = red[0];
  __syncthreads();
  return s;
}

// ---------------- KPREP: 0..24 Ws-transpose tiles; 25 bsp; 26..153 aspect(b); 154..156 guide(k)
__global__ __launch_bounds__(512) void kprep(
    const float* __restrict__ Ws, const float* __restrict__ Watt,
    const float* __restrict__ Gw, const float* __restrict__ bs,
    const float* __restrict__ gcap, const int* __restrict__ aspect,
    const float* __restrict__ embed, const float* __restrict__ Wa,
    const float* __restrict__ ba,
    unsigned short* __restrict__ wt, float* __restrict__ bsp,
    float* __restrict__ tbuf, float* __restrict__ gbuf)
{
  int bid = blockIdx.x, tid = threadIdx.x;
  int lane = tid & 63, w = tid >> 6;
  __shared__ float sh[64*65];   // reused: transpose tile / {aspL, capL, red}
  float* aspL = sh;             // [320]
  float* capL = sh + 320;       // [320]
  float* red  = sh + 640;       // [512]

  if (bid < 25) {
    // transpose Ws (64x64 tile) -> wt bf16 [n][k]
    float (*t)[65] = (float(*)[65])sh;
    int kt = bid / 5, nt = bid - kt*5;
    #pragma unroll
    for (int i = 0; i < 8; i++){
      int idx = i*512 + tid;
      int r = idx >> 6, c = idx & 63;
      int gk = kt*64 + r, gn = nt*64 + c;
      t[r][c] = (gk < ND && gn < NC) ? Ws[gk*NC + gn] : 0.f;
    }
    __syncthreads();
    #pragma unroll
    for (int i = 0; i < 8; i++){
      int idx = i*512 + tid;
      int n = idx >> 6, k = idx & 63;
      wt[(nt*64 + n)*KP + kt*64 + k] = f2bf(t[k][n]);
    }
  } else if (bid == 25) {
    if (tid < 320) bsp[tid] = (tid < NC) ? bs[tid] : 0.f;
  } else if (bid < 154) {
    int b = bid - 26;
    int a = aspect[b];
    if (tid < 320) aspL[tid] = (tid < ND) ? embed[(size_t)a*ND + tid] : 0.f;
    __syncthreads();
    // z[c] per thread c, 6-way ILP over d
    int c = tid;
    float p0=0.f,p1=0.f,p2=0.f,p3=0.f,p4=0.f,p5=0.f;
    if (c < NC){
      for (int d = 0; d < 300; d += 6){
        p0 += Wa[(d+0)*NC + c]*aspL[d+0];
        p1 += Wa[(d+1)*NC + c]*aspL[d+1];
        p2 += Wa[(d+2)*NC + c]*aspL[d+2];
        p3 += Wa[(d+3)*NC + c]*aspL[d+3];
        p4 += Wa[(d+4)*NC + c]*aspL[d+4];
        p5 += Wa[(d+5)*NC + c]*aspL[d+5];
      }
    }
    float z = (c < NC) ? (ba[c] + ((p0+p1)+(p2+p3)+(p4+p5))) : 0.f;
    float sq = bsum512((c < NC) ? z*z : 0.f, red, tid);
    float ssv = (sq/(1.f+sq))/sqrtf(sq + SQ_EPS);
    if (tid < 320) capL[tid] = (c < NC) ? z*ssv : 0.f;
    __syncthreads();
    // t[c] = sum_d Watt[c][d]*cap[d], wave-per-c
    for (int cc = w; cc < NC; cc += 8){
      const float* wr = Watt + (size_t)cc*NC;
      float acc = 0.f;
      #pragma unroll
      for (int j = 0; j < 5; j++){
        int d = j*64 + lane;
        float wv = (d < ND) ? wr[d] : 0.f;
        acc += wv*capL[d];
      }
      #pragma unroll
      for (int off = 32; off > 0; off >>= 1) acc += __shfl_xor(acc, off);
      if (lane == 0) tbuf[(size_t)b*CP + cc] = acc;
    }
    if (tid < 4) tbuf[(size_t)b*CP + NC + tid] = 0.f;
  } else {
    int k = bid - 154;   // 0..2
    if (tid < 320) aspL[tid] = (tid < NC) ? gcap[k*NC + tid] : 0.f;
    __syncthreads();
    float g = (tid < 320) ? aspL[tid] : 0.f;
    float sq = bsum512((tid < NC) ? g*g : 0.f, red, tid);
    float ssv = (sq/(1.f+sq))/sqrtf(sq + SQ_EPS);
    if (tid < 320) capL[tid] = g*ssv;
    __syncthreads();
    for (int cc = w; cc < NC; cc += 8){
      const float* wr = Gw + (size_t)cc*NC;
      float acc = 0.f;
      #pragma unroll
      for (int j = 0; j < 5; j++){
        int d = j*64 + lane;
        float wv = (d < ND) ? wr[d] : 0.f;
        acc += wv*capL[d];
      }
      #pragma unroll
      for (int off = 32; off > 0; off >>= 1) acc += __shfl_xor(acc, off);
      if (lane == 0) gbuf[(size_t)k*CP + cc] = acc;
    }
    if (tid < 4) gbuf[(size_t)k*CP + NC + tid] = 0.f;
  }
}

// ---------------- K1: E = embed @ W_s (bf16 MFMA) + per-row e.e into EtT col 132
#define BM 64
#define BKT 64
#define LDK 72
__global__ __launch_bounds__(512) void k1_gemm(
    const float* __restrict__ embed, const unsigned short* __restrict__ wt,
    unsigned short* __restrict__ E, float* __restrict__ EtT)
{
  __shared__ unsigned short lds_a[BM*LDK];
  __shared__ unsigned short lds_b[KP*LDK];
  __shared__ float e2part[4][BM];
  int tid = threadIdx.x;
  int lane = tid & 63, wid = tid >> 6;
  int wrow = wid >> 2, wcol = wid & 3;
  int rowbase = blockIdx.x * BM;
  f32x4 acc[2][5];
  f32x4 zero = {0.f,0.f,0.f,0.f};
  #pragma unroll
  for (int m = 0; m < 2; m++)
    #pragma unroll
    for (int n = 0; n < 5; n++) acc[m][n] = zero;

  for (int k0 = 0; k0 < KP; k0 += BKT){
    #pragma unroll
    for (int r = 0; r < 2; r++){
      int id = r*512 + tid;                 // < 1024
      int row = id >> 4, k4 = (id & 15) << 2;
      int gk = k0 + k4, grow = rowbase + row;
      float4 v = {0.f,0.f,0.f,0.f};
      if (grow < NV && gk < ND) v = *(const float4*)(embed + (size_t)grow*ND + gk);
      unsigned int lo = (unsigned int)f2bf(v.x) | ((unsigned int)f2bf(v.y) << 16);
      unsigned int hi = (unsigned int)f2bf(v.z) | ((unsigned int)f2bf(v.w) << 16);
      uint2 pk; pk.x = lo; pk.y = hi;
      *(uint2*)(lds_a + row*LDK + k4) = pk;
    }
    #pragma unroll
    for (int r = 0; r < 5; r++){
      int id = r*512 + tid;                 // < 2560
      int n = id >> 3, koff = (id & 7) << 3;
      uint4 v = *(const uint4*)(wt + n*KP + k0 + koff);
      *(uint4*)(lds_b + n*LDK + koff) = v;
    }
    __syncthreads();
    #pragma unroll
    for (int kk = 0; kk < BKT; kk += 32){
      bf16x8 af[2], bfr[5];
      int kidx = kk + (lane >> 4)*8;
      int arow = wrow*32 + (lane & 15);
      int brow = wcol*80 + (lane & 15);
      #pragma unroll
      for (int m = 0; m < 2; m++) af[m] = *(const bf16x8*)(lds_a + (arow + m*16)*LDK + kidx);
      #pragma unroll
      for (int n = 0; n < 5; n++) bfr[n] = *(const bf16x8*)(lds_b + (brow + n*16)*LDK + kidx);
      #pragma unroll
      for (int m = 0; m < 2; m++)
        #pragma unroll
        for (int n = 0; n < 5; n++)
          acc[m][n] = __builtin_amdgcn_mfma_f32_16x16x32_bf16(af[m], bfr[n], acc[m][n], 0, 0, 0);
    }
    __syncthreads();
  }
  int colb = wcol*80 + (lane & 15);
  int rowb = rowbase + wrow*32 + ((lane >> 4) << 2);
  #pragma unroll
  for (int m = 0; m < 2; m++)
    #pragma unroll
    for (int n = 0; n < 5; n++)
      #pragma unroll
      for (int j = 0; j < 4; j++){
        int row = rowb + m*16 + j;
        int col = colb + n*16;
        if (row < NV) E[(size_t)row*EP + col] = f2bf(acc[m][n][j]);
      }
  #pragma unroll
  for (int m = 0; m < 2; m++)
    #pragma unroll
    for (int j = 0; j < 4; j++){
      float p = 0.f;
      #pragma unroll
      for (int n = 0; n < 5; n++){ float t = acc[m][n][j]; p += t*t; }
      #pragma unroll
      for (int off = 1; off < 16; off <<= 1) p += __shfl_xor(p, off);
      if ((lane & 15) == 0)
        e2part[wcol][wrow*32 + m*16 + ((lane >> 4) << 2) + j] = p;
    }
  __syncthreads();
  if (tid < BM){
    int grow = rowbase + tid;
    if (grow < NV){
      float s = e2part[0][tid] + e2part[1][tid] + e2part[2][tid] + e2part[3][tid];
      EtT[(size_t)grow*ETW + 132] = s;
    }
  }
}

// ---------------- K1B: EtT[:,0:132] = [E ; bs] @ [T | g0 g1 g2 | bs]^T
#define BM2 128
#define BN2 160
#define LDK2 72
__global__ __launch_bounds__(512) void k1b_gemm(
    const unsigned short* __restrict__ E, const float* __restrict__ tbuf,
    const float* __restrict__ gbuf, const float* __restrict__ bsp,
    float* __restrict__ EtT)
{
  __shared__ unsigned short la[BM2*LDK2];
  __shared__ unsigned short lb[BN2*LDK2];
  int tid = threadIdx.x;
  int lane = tid & 63, wid = tid >> 6;
  int wrow = wid >> 1, wcol = wid & 1;    // 4 x 2
  int rowbase = blockIdx.x * BM2;
  f32x4 acc[2][5];
  f32x4 zero = {0.f,0.f,0.f,0.f};
  #pragma unroll
  for (int m = 0; m < 2; m++)
    #pragma unroll
    for (int n = 0; n < 5; n++) acc[m][n] = zero;

  for (int k0 = 0; k0 < EP; k0 += 64){
    #pragma unroll
    for (int r = 0; r < 2; r++){
      int id = r*512 + tid;                 // < 1024
      int row = id >> 3, koff = (id & 7) << 3;
      int grow = rowbase + row, gk = k0 + koff;
      uint4 v = {0u,0u,0u,0u};
      if (grow < NV){
        v = *(const uint4*)(E + (size_t)grow*EP + gk);
      } else if (grow == NV){
        float4 f0 = *(const float4*)(bsp + gk);
        float4 f1 = *(const float4*)(bsp + gk + 4);
        v.x = (unsigned int)f2bf(f0.x) | ((unsigned int)f2bf(f0.y) << 16);
        v.y = (unsigned int)f2bf(f0.z) | ((unsigned int)f2bf(f0.w) << 16);
        v.z = (unsigned int)f2bf(f1.x) | ((unsigned int)f2bf(f1.y) << 16);
        v.w = (unsigned int)f2bf(f1.z) | ((unsigned int)f2bf(f1.w) << 16);
      }
      *(uint4*)(la + row*LDK2 + koff) = v;
    }
    #pragma unroll
    for (int r = 0; r < 5; r++){
      int id = r*512 + tid;                 // < 2560
      int n = id >> 4, k4 = (id & 15) << 2;
      int gk = k0 + k4;
      float4 f = {0.f,0.f,0.f,0.f};
      if (gk < CP){
        if (n < 128)       f = *(const float4*)(tbuf + (size_t)n*CP + gk);
        else if (n < 131)  f = *(const float4*)(gbuf + (size_t)(n-128)*CP + gk);
        else if (n == 131) f = *(const float4*)(bsp + gk);
      }
      uint2 pk;
      pk.x = (unsigned int)f2bf(f.x) | ((unsigned int)f2bf(f.y) << 16);
      pk.y = (unsigned int)f2bf(f.z) | ((unsigned int)f2bf(f.w) << 16);
      *(uint2*)(lb + n*LDK2 + k4) = pk;
    }
    __syncthreads();
    #pragma unroll
    for (int kk = 0; kk < 64; kk += 32){
      bf16x8 af[2], bfr[5];
      int kidx = kk + (lane >> 4)*8;
      int arow = wrow*32 + (lane & 15);
      int brow = wcol*80 + (lane & 15);
      #pragma unroll
      for (int m = 0; m < 2; m++) af[m] = *(const bf16x8*)(la + (arow + m*16)*LDK2 + kidx);
      #pragma unroll
      for (int n = 0; n < 5; n++) bfr[n] = *(const bf16x8*)(lb + (brow + n*16)*LDK2 + kidx);
      #pragma unroll
      for (int m = 0; m < 2; m++)
        #pragma unroll
        for (int n = 0; n < 5; n++)
          acc[m][n] = __builtin_amdgcn_mfma_f32_16x16x32_bf16(af[m], bfr[n], acc[m][n], 0, 0, 0);
    }
    __syncthreads();
  }
  int colb = wcol*80 + (lane & 15);
  int rowb = rowbase + wrow*32 + ((lane >> 4) << 2);
  #pragma unroll
  for (int m = 0; m < 2; m++)
    #pragma unroll
    for (int n = 0; n < 5; n++)
      #pragma unroll
      for (int j = 0; j < 4; j++){
        int row = rowb + m*16 + j;
        int col = colb + n*16;
        if (row <= NV && col < 132) EtT[(size_t)row*ETW + col] = acc[m][n][j];
      }
}

// ---------------- K45: per-b stats -> softmax -> weighted E-row gather -> out
__global__ __launch_bounds__(512) void k45(
    const int* __restrict__ sentence, const float* __restrict__ alpha,
    const float* __restrict__ scale_p, const unsigned short* __restrict__ E,
    const float* __restrict__ EtT, const float* __restrict__ bsp,
    float* __restrict__ out)
{
  int b = blockIdx.x, tid = threadIdx.x;
  int lane = tid & 63, w = tid >> 6;
  __shared__ float red[512];
  __shared__ float cfs[NS*3];
  __shared__ int toksh[NS];
  __shared__ float cap8[8][3][CP];
  __shared__ float vall[3*CP];

  int idx = (b << 9) + tid;
  int tok = sentence[idx];
  float al = alpha[idx];
  toksh[tid] = tok;
  const float* er = EtT + (size_t)tok*ETW;
  float e2v = er[132];
  float et  = er[b];
  float g0  = er[128], g1 = er[129], g2 = er[130];
  float ebs = er[131];
  const float* br = EtT + (size_t)NV*ETW;
  float bst = br[b];
  float bsg0 = br[128], bsg1 = br[129], bsg2 = br[130], bs2 = br[131];

  float sq  = al*al*e2v + 2.f*al*ebs + bs2;
  float ssv = (sq/(1.f+sq))/sqrtf(sq + SQ_EPS);
  float scv = (tok != 0) ? ssv*(al*et + bst) : MASK_NEG;
  float u0 = ssv*(al*g0 + bsg0);
  float u1 = ssv*(al*g1 + bsg1);
  float u2 = ssv*(al*g2 + bsg2);

  float m = bmax512(scv, red, tid);
  float e = expf(scv - m);
  float Z = bsum512(e, red, tid);
  float nw = e / Z;
  float mk = fmaxf(u0, fmaxf(u1, u2));
  float e0 = expf(u0-mk), e1 = expf(u1-mk), e2 = expf(u2-mk);
  float wf = nw * scale_p[0] / (e0+e1+e2);
  float w0 = e0*wf, w1 = e1*wf, w2 = e2*wf;
  float ca = ssv * al;
  cfs[tid*3+0] = w0*ca; cfs[tid*3+1] = w1*ca; cfs[tid*3+2] = w2*ca;
  float sb0 = bsum512(w0*ssv, red, tid);
  float sb1 = bsum512(w1*ssv, red, tid);
  float sb2 = bsum512(w2*ssv, red, tid);
  __syncthreads();

  f32x4 A0 = {0.f,0.f,0.f,0.f}, A1 = A0, A2 = A0, R0 = A0, R1 = A0, R2 = A0;
  int c0 = lane << 2;
  int c1 = 256 + (lane << 2);
  bool rem = lane < 12;
  int base = w << 6;
  #pragma unroll 4
  for (int i = 0; i < 64; i++){
    int s = base + i;
    int t = toksh[s];
    const unsigned short* erow = E + (size_t)t*EP;
    uint2 ev = *(const uint2*)(erow + c0);
    float cf0 = cfs[s*3+0], cf1 = cfs[s*3+1], cf2 = cfs[s*3+2];
    f32x4 y;
    y[0] = bf2f((unsigned short)(ev.x & 0xffffu));
    y[1] = bf2f((unsigned short)(ev.x >> 16));
    y[2] = bf2f((unsigned short)(ev.y & 0xffffu));
    y[3] = bf2f((unsigned short)(ev.y >> 16));
    A0 += cf0*y; A1 += cf1*y; A2 += cf2*y;
    if (rem){
      uint2 ev2 = *(const uint2*)(erow + c1);
      f32x4 yr;
      yr[0] = bf2f((unsigned short)(ev2.x & 0xffffu));
      yr[1] = bf2f((unsigned short)(ev2.x >> 16));
      yr[2] = bf2f((unsigned short)(ev2.y & 0xffffu));
      yr[3] = bf2f((unsigned short)(ev2.y >> 16));
      R0 += cf0*yr; R1 += cf1*yr; R2 += cf2*yr;
    }
  }
  *(f32x4*)&cap8[w][0][c0] = A0;
  *(f32x4*)&cap8[w][1][c0] = A1;
  *(f32x4*)&cap8[w][2][c0] = A2;
  if (rem){
    *(f32x4*)&cap8[w][0][c1] = R0;
    *(f32x4*)&cap8[w][1][c1] = R1;
    *(f32x4*)&cap8[w][2][c1] = R2;
  }
  __syncthreads();
  float sbk[3] = {sb0, sb1, sb2};
  for (int p = tid; p < 3*CP; p += 512){
    int k = p / CP, c = p - k*CP;
    float v = sbk[k]*bsp[c];
    #pragma unroll
    for (int w8 = 0; w8 < 8; w8++) v += cap8[w8][k][c];
    vall[p] = v;
  }
  __syncthreads();
  #pragma unroll
  for (int k = 0; k < 3; k++){
    float x = 0.f;
    if (tid < CP){ float t = vall[k*CP + tid]; x = t*t; }
    float s = bsum512(x, red, tid);
    if (tid == 0){
      out[b*3 + k] = (s/(1.f+s))*sqrtf(s)/sqrtf(s + SQ_EPS);
    }
  }
}

extern "C" void kernel_launch(void* const* d_in, const int* in_sizes, int n_in,
                              void* d_out, int out_size, void* d_ws, size_t ws_size,
                              hipStream_t stream)
{
  (void)in_sizes; (void)n_in; (void)out_size; (void)ws_size;
  const int*   sentence = (const int*)d_in[0];
  const int*   aspect   = (const int*)d_in[1];
  const float* alpha    = (const float*)d_in[2];
  const float* embed    = (const float*)d_in[3];
  const float* Ws       = (const float*)d_in[4];
  const float* bs       = (const float*)d_in[5];
  const float* Wa       = (const float*)d_in[6];
  const float* ba       = (const float*)d_in[7];
  const float* Watt     = (const float*)d_in[8];
  const float* gcap     = (const float*)d_in[9];
  const float* gw       = (const float*)d_in[10];
  const float* scale    = (const float*)d_in[11];
  float* out = (float*)d_out;

  char* w = (char*)d_ws;
  auto alloc = [&](size_t bytes)->char*{
    char* p = w; w += (bytes + 255) & ~(size_t)255; return p;
  };
  unsigned short* WT  = (unsigned short*)alloc((size_t)KP*KP*2);
  unsigned short* E   = (unsigned short*)alloc((size_t)NV*EP*2);
  float* ETT = (float*)alloc((size_t)(NV+1)*ETW*4);
  float* BSP = (float*)alloc(320*4);
  float* TBF = (float*)alloc((size_t)NB*CP*4);
  float* GBF = (float*)alloc(3*CP*4);

  kprep<<<157, 512, 0, stream>>>(Ws, Watt, gw, bs, gcap, aspect, embed, Wa, ba,
                                 WT, BSP, TBF, GBF);
  k1_gemm<<<(NV + BM - 1)/BM, 512, 0, stream>>>(embed, WT, E, ETT);
  k1b_gemm<<<(NV + 1 + BM2 - 1)/BM2, 512, 0, stream>>>(E, TBF, GBF, BSP, ETT);
  k45<<<NB, 512, 0, stream>>>(sentence, alpha, scale, E, ETT, BSP, out);
}